// Round 5
// baseline (101.616 us; speedup 1.0000x reference)
//
#include <hip/hip_runtime.h>

// B=16, N=2048, C=128, S=25, D_AGG=128, D_OUT=128
// in: A[16,2048,2048] f32, X[16,2048,128] f32, Wa[128,128] f32, ba[128] f32,
//     Wc[256,128] f32, bc[128] f32, n_samples i32
// out: [16,2048,128] f32
//
// Pipeline:
//   prep    : Wa->Wat bf16^T, Wc->Wct bf16^T, sentinel H row = relu(ba)
//   scanK1  : blocks 0..255  = K1 GEMM H = relu(X@Wa+ba) (bf16, MFMA)
//             blocks 256..8447 = A-row ballot-rank scan -> padded idx lists
//             (independent work items fused into one launch; K1 hides under
//              the 256 MB A stream)
//   gather  : agg[node] = max over 32 idx'd H rows (sentinel-padded,
//             batch-affine XCD mapping for H L2 locality)
//   K3      : out = relu([X|agg] @ Wc + bc) -> f32 + partial sumsq (MFMA)
//   K5      : out *= 1/frobnorm per batch (div_no_nan)
//
// ws: H 8MB+4K @0 (32769 rows: last = sentinel), agg 8MB @8M+4K,
//     idxg 2MB @16M+8K, Wat 32K @18M+12K, Wct 64K @+32K, partials @+96K

typedef __attribute__((ext_vector_type(8))) short short8;   // bf16x8 raw bits
typedef __attribute__((ext_vector_type(4))) float f32x4;
typedef __attribute__((ext_vector_type(4))) float fvec4;
typedef unsigned int uint;
typedef unsigned short ushort;

__device__ __forceinline__ ushort f2bf(float x) {           // RNE f32->bf16
    uint u = __builtin_bit_cast(uint, x);
    u += 0x7FFFu + ((u >> 16) & 1u);
    return (ushort)(u >> 16);
}
__device__ __forceinline__ float bflo(uint h) { uint v = h << 16;         return __builtin_bit_cast(float, v); }
__device__ __forceinline__ float bfhi(uint h) { uint v = h & 0xFFFF0000u; return __builtin_bit_cast(float, v); }
// popcount(mask64 & lanemask_lt)
__device__ __forceinline__ int mbcnt64(unsigned long long m) {
    return __builtin_amdgcn_mbcnt_hi((uint)(m >> 32),
           __builtin_amdgcn_mbcnt_lo((uint)m, 0u));
}

// ---------------------------------------------------------------------------
// prep: Wat[d*128+k]=bf16(Wa[k][d]); Wct[d*256+k]=bf16(Wc[k][d]);
//       block 192: sentinel H row (index 32768) = relu(ba), bf16-pair packed.
// ---------------------------------------------------------------------------
__global__ __launch_bounds__(256) void prep_k(
    const float* __restrict__ Wa, const float* __restrict__ Wc,
    const float* __restrict__ ba,
    ushort* __restrict__ Wat, ushort* __restrict__ Wct,
    uint* __restrict__ Hsent)
{
    int i = blockIdx.x * 256 + threadIdx.x;
    if (i < 16384) {
        int d = i >> 7, k = i & 127;
        Wat[i] = f2bf(Wa[k * 128 + d]);
    } else if (i < 49152) {
        int j = i - 16384;
        int d = j >> 8, k = j & 255;
        Wct[j] = f2bf(Wc[k * 128 + d]);
    } else if (threadIdx.x < 64) {
        int t = threadIdx.x;
        float a = fmaxf(ba[2 * t], 0.f), b = fmaxf(ba[2 * t + 1], 0.f);
        Hsent[t] = (uint)f2bf(a) | ((uint)f2bf(b) << 16);
    }
}

// ---------------------------------------------------------------------------
// Shared MFMA GEMM body: 128x128 tile, 4 waves 2x2, wave = 64x64 = 4x4 frags
// of 16x16x32. Chunk0 converted from fp32, chunk1 bf16. B pre-transposed
// [col][k]. LDS XOR swizzle on 16B granules (write AND read).
// ---------------------------------------------------------------------------
__device__ __forceinline__ void gemm_body(
    const float*  __restrict__ Xf, const ushort* __restrict__ A1,
    const ushort* __restrict__ Bt, const float*  __restrict__ bias,
    ushort* __restrict__ outH, float* __restrict__ outF,
    float* __restrict__ partials, int ktiles, int tile,
    ushort* Asm, ushort* Bsm, float* wred)
{
    const int tid = threadIdx.x;
    const int l = tid & 63, w = tid >> 6;
    const int wm = (w >> 1) * 64, wn = (w & 1) * 64;
    const size_t row0 = (size_t)tile * 128;
    const int KT = ktiles << 7;

    f32x4 acc[4][4] = {};

    for (int t = 0; t < ktiles; ++t) {
        __syncthreads();
        if (t == 0) {
#pragma unroll
            for (int j = 0; j < 8; ++j) {
                int gid = (j << 8) + tid;          // 16B granule id
                int r = gid >> 4, g = gid & 15;
                const float* s = Xf + (row0 + r) * 128 + g * 8;
                short8 pk;
#pragma unroll
                for (int e = 0; e < 8; ++e) pk[e] = (short)f2bf(s[e]);
                *(short8*)&Asm[r * 128 + ((g ^ (r & 7)) << 3)] = pk;
            }
        } else {
#pragma unroll
            for (int j = 0; j < 8; ++j) {
                int gid = (j << 8) + tid;
                int r = gid >> 4, g = gid & 15;
                short8 v = *(const short8*)(A1 + (row0 + r) * 128 + g * 8);
                *(short8*)&Asm[r * 128 + ((g ^ (r & 7)) << 3)] = v;
            }
        }
#pragma unroll
        for (int j = 0; j < 8; ++j) {
            int gid = (j << 8) + tid;
            int r = gid >> 4, g = gid & 15;
            short8 v = *(const short8*)(Bt + (size_t)r * KT + (t << 7) + g * 8);
            *(short8*)&Bsm[r * 128 + ((g ^ (r & 7)) << 3)] = v;
        }
        __syncthreads();
#pragma unroll
        for (int ks = 0; ks < 4; ++ks) {
            int gg = (ks << 2) + (l >> 4);
            short8 af[4], bfr[4];
#pragma unroll
            for (int m = 0; m < 4; ++m) {
                int r = wm + m * 16 + (l & 15);
                af[m] = *(const short8*)&Asm[r * 128 + ((gg ^ (r & 7)) << 3)];
            }
#pragma unroll
            for (int n = 0; n < 4; ++n) {
                int c = wn + n * 16 + (l & 15);
                bfr[n] = *(const short8*)&Bsm[c * 128 + ((gg ^ (c & 7)) << 3)];
            }
#pragma unroll
            for (int m = 0; m < 4; ++m)
#pragma unroll
                for (int n = 0; n < 4; ++n)
                    acc[m][n] = __builtin_amdgcn_mfma_f32_16x16x32_bf16(
                        af[m], bfr[n], acc[m][n], 0, 0, 0);
        }
    }

    float bcol[4];
#pragma unroll
    for (int n = 0; n < 4; ++n) bcol[n] = bias[wn + n * 16 + (l & 15)];
    float lsum = 0.f;
#pragma unroll
    for (int m = 0; m < 4; ++m) {
        int rbase = wm + m * 16 + ((l >> 4) << 2);   // C/D: row = 4*(l>>4)+reg
#pragma unroll
        for (int n = 0; n < 4; ++n) {
            int col = wn + n * 16 + (l & 15);        // C/D: col = l&15
#pragma unroll
            for (int r = 0; r < 4; ++r) {
                float v = fmaxf(acc[m][n][r] + bcol[n], 0.f);
                size_t o = (row0 + rbase + r) * 128 + col;
                if (outH) outH[o] = f2bf(v);
                else { outF[o] = v; lsum += v * v; }
            }
        }
    }
    if (partials) {
#pragma unroll
        for (int off = 32; off > 0; off >>= 1) lsum += __shfl_down(lsum, off);
        if (l == 0) wred[w] = lsum;
        __syncthreads();
        if (tid == 0) partials[tile] = wred[0] + wred[1] + wred[2] + wred[3];
    }
}

// ---------------------------------------------------------------------------
// scanK1: blocks 0..255 compute K1 GEMM (H = relu(X@Wa+ba), bf16).
// Blocks 256..8447: one wave per node; ballot-rank scan of the A row yields
// the first min(deg,S) nonzero indices in ascending order (== lax.top_k of
// the binary mask); writes a 32-slot padded GLOBAL index list (pad = first
// index if any, else sentinel 32768 -> relu(ba) row).
// ---------------------------------------------------------------------------
__global__ __launch_bounds__(256) void scanK1_k(
    const float* __restrict__ A,        // [32768][2048]
    const float* __restrict__ X,
    const ushort* __restrict__ Wat,
    const float* __restrict__ ba,
    ushort* __restrict__ H,             // [32769][128] bf16 (last = sentinel)
    ushort* __restrict__ idxg,          // [32768][32] padded global indices
    const int* __restrict__ nsp)
{
    __shared__ ushort Asm[128 * 128];
    __shared__ ushort Bsm[128 * 128];
    __shared__ float wred[4];

    if (blockIdx.x < 256) {             // K1 GEMM path
        gemm_body(X, nullptr, Wat, ba, H, nullptr, nullptr, 1, blockIdx.x,
                  Asm, Bsm, wred);
        return;
    }

    const int sid = blockIdx.x - 256;
    const int l = threadIdx.x & 63;
    const int w = threadIdx.x >> 6;
    const int node = sid * 4 + w;
    int S = nsp[0]; if (S > 32) S = 32;
    int* idxs = (int*)Bsm;              // [4][32]

    const fvec4* rowp = (const fvec4*)(A + (size_t)node * 2048);
    fvec4 v[8];
#pragma unroll
    for (int c = 0; c < 8; ++c)
        v[c] = __builtin_nontemporal_load(rowp + c * 64 + l);

    const int gbase = node & ~2047;     // batch<<11
    int base = 0;
#pragma unroll
    for (int c = 0; c < 8; ++c) {
        if (base < S) {                              // wave-uniform skip
            unsigned long long m0 = __ballot(v[c][0] != 0.f);
            unsigned long long m1 = __ballot(v[c][1] != 0.f);
            unsigned long long m2 = __ballot(v[c][2] != 0.f);
            unsigned long long m3 = __ballot(v[c][3] != 0.f);
            int below = mbcnt64(m0) + mbcnt64(m1) + mbcnt64(m2) + mbcnt64(m3);
            int o0 = (int)((m0 >> l) & 1), o1 = (int)((m1 >> l) & 1);
            int o2 = (int)((m2 >> l) & 1), o3 = (int)((m3 >> l) & 1);
            int r0 = base + below;
            int r1 = r0 + o0, r2 = r1 + o1, r3 = r2 + o2;
            int e = gbase + (c << 8) + (l << 2);
            if (o0 && r0 < S) idxs[w * 32 + r0] = e;
            if (o1 && r1 < S) idxs[w * 32 + r1] = e + 1;
            if (o2 && r2 < S) idxs[w * 32 + r2] = e + 2;
            if (o3 && r3 < S) idxs[w * 32 + r3] = e + 3;
            base += __popcll(m0) + __popcll(m1) + __popcll(m2) + __popcll(m3);
        }
    }
    int found = base < S ? base : S;
    int fill = (found > 0) ? idxs[w * 32] : 32768;   // sentinel if degree 0
    if (l < 32) {
        int val = (l < found) ? idxs[w * 32 + l] : fill;
        idxg[(size_t)node * 32 + l] = (ushort)val;
    }
}

// ---------------------------------------------------------------------------
// gather: one wave per node (batch-affine XCD mapping: batch = {xcd, xcd+8}
// so each XCD's L2 holds only its own 512 KB H slices). Branch-free 32-way
// gather-max of H rows via the padded index list. acc init = relu(ba).
// ---------------------------------------------------------------------------
__global__ __launch_bounds__(256) void gather_k(
    const ushort* __restrict__ idxg,    // [32768][32]
    const uint*  __restrict__ Hu,       // [32769][64] bf16 pairs
    const float* __restrict__ ba,
    uint* __restrict__ aggu)            // [32768][64] bf16 pairs
{
    __shared__ ushort sidx[128];        // 4 nodes x 32
    const int l = threadIdx.x & 63;
    const int w = threadIdx.x >> 6;
    const int bid = blockIdx.x, xcd = bid & 7, grp = bid >> 3;
    const int batch = ((grp >> 9) << 3) + xcd;       // 0..15
    const int node0 = (batch << 11) + ((grp & 511) << 2);
    const int node = node0 + w;

    if (threadIdx.x < 64)
        ((uint*)sidx)[threadIdx.x] =
            ((const uint*)(idxg + (size_t)node0 * 32))[threadIdx.x];
    __syncthreads();

    uint h[32];
#pragma unroll
    for (int q = 0; q < 32; ++q)                     // all 32 in flight
        h[q] = Hu[(size_t)sidx[w * 32 + q] * 64 + l];

    float i0 = fmaxf(ba[2 * l], 0.f), i1 = fmaxf(ba[2 * l + 1], 0.f);
    float a0[8], a1[8];
#pragma unroll
    for (int q = 0; q < 8; ++q) { a0[q] = i0; a1[q] = i1; }
#pragma unroll
    for (int q = 0; q < 32; ++q) {
        a0[q & 7] = fmaxf(a0[q & 7], bflo(h[q]));
        a1[q & 7] = fmaxf(a1[q & 7], bfhi(h[q]));
    }
#pragma unroll
    for (int q = 0; q < 4; ++q) {
        a0[q] = fmaxf(a0[q], a0[q + 4]);
        a1[q] = fmaxf(a1[q], a1[q + 4]);
    }
    float r0f = fmaxf(fmaxf(a0[0], a0[1]), fmaxf(a0[2], a0[3]));
    float r1f = fmaxf(fmaxf(a1[0], a1[1]), fmaxf(a1[2], a1[3]));
    aggu[(size_t)node * 64 + l] = (uint)f2bf(r0f) | ((uint)f2bf(r1f) << 16);
}

// ---------------------------------------------------------------------------
// K3: standalone GEMM kernel (wraps gemm_body, ktiles=2)
// ---------------------------------------------------------------------------
__global__ __launch_bounds__(256) void gemm_k3_k(
    const float* __restrict__ X, const ushort* __restrict__ agg,
    const ushort* __restrict__ Wct, const float* __restrict__ bc,
    float* __restrict__ out, float* __restrict__ partials)
{
    __shared__ ushort Asm[128 * 128];
    __shared__ ushort Bsm[128 * 128];
    __shared__ float wred[4];
    gemm_body(X, agg, Wct, bc, nullptr, out, partials, 2, blockIdx.x,
              Asm, Bsm, wred);
}

// ---------------------------------------------------------------------------
// K5: per-batch frobenius normalize in place; each block deterministically
// reduces its batch's 16 partials. div_no_nan: norm==0 -> 0.
// ---------------------------------------------------------------------------
__global__ __launch_bounds__(256) void scale_k(
    float* __restrict__ out, const float* __restrict__ partials)
{
    const int blk = blockIdx.x;
    const int b = blk >> 6;                          // 64 blocks per batch
    float s = 0.f;
#pragma unroll
    for (int i = 0; i < 16; ++i) s += partials[b * 16 + i];
    float norm = sqrtf(s);
    float sc = (norm > 0.f) ? (1.f / norm) : 0.f;
    fvec4* o4 = (fvec4*)out;
    int i0 = blk * 1024 + threadIdx.x;
#pragma unroll
    for (int k = 0; k < 4; ++k) {
        fvec4 v = o4[i0 + k * 256];
        o4[i0 + k * 256] = v * sc;
    }
}

extern "C" void kernel_launch(void* const* d_in, const int* in_sizes, int n_in,
                              void* d_out, int out_size, void* d_ws, size_t ws_size,
                              hipStream_t stream) {
    const float* A  = (const float*)d_in[0];
    const float* X  = (const float*)d_in[1];
    const float* Wa = (const float*)d_in[2];
    const float* ba = (const float*)d_in[3];
    const float* Wc = (const float*)d_in[4];
    const float* bc = (const float*)d_in[5];
    const int*  nsp = (const int*)d_in[6];

    float* out = (float*)d_out;
    char* ws = (char*)d_ws;
    ushort* H        = (ushort*)ws;                               // 8MB+256B
    ushort* agg      = (ushort*)(ws + (8u << 20) + 4096);         // 8 MB
    ushort* idxg     = (ushort*)(ws + (16u << 20) + 8192);        // 2 MB
    ushort* Wat      = (ushort*)(ws + (18u << 20) + 12288);       // 32 KB
    ushort* Wct      = (ushort*)(ws + (18u << 20) + 12288 + 32768);   // 64 KB
    float*  partials = (float*) (ws + (18u << 20) + 12288 + 98304);  // 1 KB

    // weights -> bf16 transposed + sentinel H row (index 32768)
    prep_k<<<193, 256, 0, stream>>>(Wa, Wc, ba, Wat, Wct,
                                    (uint*)H + (size_t)32768 * 64);
    // K1 GEMM (blocks 0..255) + A-row scan (blocks 256..8447), independent
    scanK1_k<<<8448, 256, 0, stream>>>(A, X, Wat, ba, H, idxg, nsp);
    // agg = max over idx'd H rows
    gather_k<<<8192, 256, 0, stream>>>(idxg, (const uint*)H, ba, (uint*)agg);
    // K3: out = relu([X|agg] @ Wc + bc) + partial sumsq
    gemm_k3_k<<<256, 256, 0, stream>>>(X, agg, Wct, bc, out, partials);
    // K5: normalize
    scale_k<<<1024, 256, 0, stream>>>(out, partials);
}

// Round 6
// 90.684 us; speedup vs baseline: 1.1205x; 1.1205x over previous
//
#include <hip/hip_runtime.h>

// B=16, N=2048, C=128, S=25, D_AGG=128, D_OUT=128
// in: A[16,2048,2048] f32, X[16,2048,128] f32, Wa[128,128] f32, ba[128] f32,
//     Wc[256,128] f32, bc[128] f32, n_samples i32
// out: [16,2048,128] f32
//
// Pipeline (R4 structure + K5 folded into K3 via device barrier):
//   prep   : Wa -> Wat bf16^T (64 blocks) + zero barrier counter
//   K1     : H = relu(X @ Wa + ba) -> bf16 [32768][128] (MFMA)
//   K2     : agg = max over first-S neighbors of H rows (rank-scan + 32-wide
//            batched gather; batch-affine XCD mapping for H L2 locality)
//            + blocks >= 8192 prep Wc -> Wct bf16
//   K3     : out = relu([X|agg] @ Wc + bc); per-tile sumsq partials; grid
//            barrier (arrive-and-spin, device scope); normalize IN REGISTERS
//            and write final out once (div_no_nan). K5 eliminated.
//
// ws: H 8MB @0, agg 8MB @8M, Wat 32K @16M, Wct 64K @16M+32K,
//     partials 1K @16M+128K, ctr @16M+132K

typedef __attribute__((ext_vector_type(8))) short short8;   // bf16x8 raw bits
typedef __attribute__((ext_vector_type(4))) float f32x4;
typedef __attribute__((ext_vector_type(4))) float fvec4;
typedef unsigned int uint;
typedef unsigned short ushort;

__device__ __forceinline__ ushort f2bf(float x) {           // RNE f32->bf16
    uint u = __builtin_bit_cast(uint, x);
    u += 0x7FFFu + ((u >> 16) & 1u);
    return (ushort)(u >> 16);
}
__device__ __forceinline__ float bflo(uint h) { uint v = h << 16;         return __builtin_bit_cast(float, v); }
__device__ __forceinline__ float bfhi(uint h) { uint v = h & 0xFFFF0000u; return __builtin_bit_cast(float, v); }

// ---------------------------------------------------------------------------
// prep: Wat[d*128+k] = bf16(Wa[k][d]); block 0 thread 0 zeroes barrier ctr.
// ---------------------------------------------------------------------------
__global__ __launch_bounds__(256) void prep_w_k(
    const float* __restrict__ Wa, ushort* __restrict__ Wat,
    uint* __restrict__ ctr)
{
    int i = blockIdx.x * 256 + threadIdx.x;     // < 16384
    int d = i >> 7, k = i & 127;
    Wat[i] = f2bf(Wa[k * 128 + d]);
    if (i == 0) *ctr = 0u;                      // re-zero each call (replay-safe)
}

// ---------------------------------------------------------------------------
// Shared MFMA GEMM core: 128x128 tile, 4 waves 2x2, wave = 64x64 = 4x4 frags
// of 16x16x32. Chunk0 converted from fp32, chunk1 bf16. B pre-transposed
// [col][k]. LDS XOR swizzle on 16B granules (write AND read). Accumulator
// returned in acc[4][4] (all indexing static -> stays in VGPRs).
// ---------------------------------------------------------------------------
__device__ __forceinline__ void gemm_core(
    const float*  __restrict__ Xf, const ushort* __restrict__ A1,
    const ushort* __restrict__ Bt, int ktiles, int tile,
    ushort* Asm, ushort* Bsm, f32x4 acc[4][4])
{
    const int tid = threadIdx.x;
    const int l = tid & 63, w = tid >> 6;
    const int wm = (w >> 1) * 64, wn = (w & 1) * 64;
    const size_t row0 = (size_t)tile * 128;
    const int KT = ktiles << 7;

    for (int t = 0; t < ktiles; ++t) {
        __syncthreads();
        if (t == 0) {
#pragma unroll
            for (int j = 0; j < 8; ++j) {
                int gid = (j << 8) + tid;          // 16B granule id
                int r = gid >> 4, g = gid & 15;
                const float* s = Xf + (row0 + r) * 128 + g * 8;
                short8 pk;
#pragma unroll
                for (int e = 0; e < 8; ++e) pk[e] = (short)f2bf(s[e]);
                *(short8*)&Asm[r * 128 + ((g ^ (r & 7)) << 3)] = pk;
            }
        } else {
#pragma unroll
            for (int j = 0; j < 8; ++j) {
                int gid = (j << 8) + tid;
                int r = gid >> 4, g = gid & 15;
                short8 v = *(const short8*)(A1 + (row0 + r) * 128 + g * 8);
                *(short8*)&Asm[r * 128 + ((g ^ (r & 7)) << 3)] = v;
            }
        }
#pragma unroll
        for (int j = 0; j < 8; ++j) {
            int gid = (j << 8) + tid;
            int r = gid >> 4, g = gid & 15;
            short8 v = *(const short8*)(Bt + (size_t)r * KT + (t << 7) + g * 8);
            *(short8*)&Bsm[r * 128 + ((g ^ (r & 7)) << 3)] = v;
        }
        __syncthreads();
#pragma unroll
        for (int ks = 0; ks < 4; ++ks) {
            int gg = (ks << 2) + (l >> 4);
            short8 af[4], bfr[4];
#pragma unroll
            for (int m = 0; m < 4; ++m) {
                int r = wm + m * 16 + (l & 15);
                af[m] = *(const short8*)&Asm[r * 128 + ((gg ^ (r & 7)) << 3)];
            }
#pragma unroll
            for (int n = 0; n < 4; ++n) {
                int c = wn + n * 16 + (l & 15);
                bfr[n] = *(const short8*)&Bsm[c * 128 + ((gg ^ (c & 7)) << 3)];
            }
#pragma unroll
            for (int m = 0; m < 4; ++m)
#pragma unroll
                for (int n = 0; n < 4; ++n)
                    acc[m][n] = __builtin_amdgcn_mfma_f32_16x16x32_bf16(
                        af[m], bfr[n], acc[m][n], 0, 0, 0);
        }
    }
}

// ---------------------------------------------------------------------------
// K1: H = relu(X @ Wa + ba) -> bf16
// ---------------------------------------------------------------------------
__global__ __launch_bounds__(256) void gemm_k1_k(
    const float* __restrict__ X, const ushort* __restrict__ Wat,
    const float* __restrict__ ba, ushort* __restrict__ H)
{
    __shared__ ushort Asm[128 * 128];
    __shared__ ushort Bsm[128 * 128];
    f32x4 acc[4][4] = {};
    gemm_core(X, nullptr, Wat, 1, blockIdx.x, Asm, Bsm, acc);

    const int tid = threadIdx.x, l = tid & 63, w = tid >> 6;
    const int wm = (w >> 1) * 64, wn = (w & 1) * 64;
    const size_t row0 = (size_t)blockIdx.x * 128;
    float bcol[4];
#pragma unroll
    for (int n = 0; n < 4; ++n) bcol[n] = ba[wn + n * 16 + (l & 15)];
#pragma unroll
    for (int m = 0; m < 4; ++m) {
        int rbase = wm + m * 16 + ((l >> 4) << 2);   // C/D: row = 4*(l>>4)+reg
#pragma unroll
        for (int n = 0; n < 4; ++n) {
            int col = wn + n * 16 + (l & 15);        // C/D: col = l&15
#pragma unroll
            for (int r = 0; r < 4; ++r) {
                float v = fmaxf(acc[m][n][r] + bcol[n], 0.f);
                H[(row0 + rbase + r) * 128 + col] = f2bf(v);
            }
        }
    }
}

// ---------------------------------------------------------------------------
// K2: one wave per node (R4-proven). Batch-affine XCD mapping (batch =
// {xcd, xcd+8}) keeps each batch's 512 KB H slice in one L2. Rank-based
// ballot scan -> first min(deg,S) ascending indices (== lax.top_k of binary
// mask) -> LDS; pad to 32 with idxs[0] (max idempotent); 32 gathers all in
// flight. acc init = relu(ba) (= padded slot value). A loads nontemporal.
// Blocks >= 8192: Wct[d*256+k] = bf16(Wc[k][d]) prep for K3.
// ---------------------------------------------------------------------------
__global__ __launch_bounds__(256) void agg_k(
    const float* __restrict__ A,        // [32768][2048]
    const uint*  __restrict__ Hu,       // [32768][64] (bf16 pairs)
    const float* __restrict__ ba,
    uint* __restrict__ aggu,            // [32768][64] (bf16 pairs)
    const int* __restrict__ nsp,
    const float* __restrict__ Wc,       // for folded prep
    ushort* __restrict__ Wct)
{
    if (blockIdx.x >= 8192) {           // folded Wct prep: 128 blocks
        int j = (blockIdx.x - 8192) * 256 + threadIdx.x;   // < 32768
        int d = j >> 8, k = j & 255;
        Wct[j] = f2bf(Wc[k * 128 + d]);
        return;
    }

    __shared__ int idxs[4][32];
    const int l = threadIdx.x & 63;
    const int w = threadIdx.x >> 6;
    const int bid   = blockIdx.x;
    const int xcd   = bid & 7;
    const int grp   = bid >> 3;                  // 0..1023
    const int batch = ((grp >> 9) << 3) + xcd;   // 0..15
    const int node  = (batch << 11) + ((grp & 511) << 2) + w;
    int S = nsp[0]; if (S > 32) S = 32;

    const fvec4* rowp = (const fvec4*)(A + (size_t)node * 2048);
    fvec4 v[8];
#pragma unroll
    for (int c = 0; c < 8; ++c)
        v[c] = __builtin_nontemporal_load(rowp + c * 64 + l);

    const unsigned long long lt = (1ull << l) - 1ull;
    int base = 0;
#pragma unroll
    for (int c = 0; c < 8; ++c) {
        if (base < S) {                              // wave-uniform skip
            unsigned long long m0 = __ballot(v[c][0] != 0.f);
            unsigned long long m1 = __ballot(v[c][1] != 0.f);
            unsigned long long m2 = __ballot(v[c][2] != 0.f);
            unsigned long long m3 = __ballot(v[c][3] != 0.f);
            int below = __popcll(m0 & lt) + __popcll(m1 & lt)
                      + __popcll(m2 & lt) + __popcll(m3 & lt);
            int o0 = (int)((m0 >> l) & 1), o1 = (int)((m1 >> l) & 1);
            int o2 = (int)((m2 >> l) & 1), o3 = (int)((m3 >> l) & 1);
            int r0 = base + below;
            int r1 = r0 + o0, r2 = r1 + o1, r3 = r2 + o2;
            int e = (c << 8) + (l << 2);
            if (o0 && r0 < S) idxs[w][r0] = e;
            if (o1 && r1 < S) idxs[w][r1] = e + 1;
            if (o2 && r2 < S) idxs[w][r2] = e + 2;
            if (o3 && r3 < S) idxs[w][r3] = e + 3;
            base += __popcll(m0) + __popcll(m1) + __popcll(m2) + __popcll(m3);
        }
    }
    int found = base < S ? base : S;

    float i0 = fmaxf(ba[2 * l], 0.f), i1 = fmaxf(ba[2 * l + 1], 0.f);
    float r0f = i0, r1f = i1;
    if (found > 0) {
        int fill = idxs[w][0];                       // broadcast read
        if (l < 32)                                  // pad list to 32
            idxs[w][l] = (l < found) ? idxs[w][l] : fill;

        const uint* HB = Hu + ((size_t)batch << 17); // batch*2048*64
        uint h[32];
#pragma unroll
        for (int q = 0; q < 32; ++q)                 // all 32 in flight
            h[q] = HB[(size_t)idxs[w][q] * 64 + l];

        float a0[8], a1[8];
#pragma unroll
        for (int q = 0; q < 8; ++q) { a0[q] = i0; a1[q] = i1; }
#pragma unroll
        for (int q = 0; q < 32; ++q) {
            a0[q & 7] = fmaxf(a0[q & 7], bflo(h[q]));
            a1[q & 7] = fmaxf(a1[q & 7], bfhi(h[q]));
        }
#pragma unroll
        for (int q = 0; q < 4; ++q) {
            a0[q] = fmaxf(a0[q], a0[q + 4]);
            a1[q] = fmaxf(a1[q], a1[q + 4]);
        }
        r0f = fmaxf(fmaxf(a0[0], a0[1]), fmaxf(a0[2], a0[3]));
        r1f = fmaxf(fmaxf(a1[0], a1[1]), fmaxf(a1[2], a1[3]));
    }
    aggu[(size_t)node * 64 + l] = (uint)f2bf(r0f) | ((uint)f2bf(r1f) << 16);
}

// ---------------------------------------------------------------------------
// K3: out = relu([X|agg] @ Wc + bc), then grid barrier, then in-register
// frobenius normalize (div_no_nan) and single final store. Barrier: 256
// blocks, worst-case 1 block/CU x 256 CUs co-resident -> arrive-and-spin is
// deadlock-free. Release/acquire via the counter; partials read after
// acquire. Each block sums its batch's 16 partials in fixed order (determ).
// ---------------------------------------------------------------------------
__global__ __launch_bounds__(256) void gemm_k3_k(
    const float* __restrict__ X, const ushort* __restrict__ agg,
    const ushort* __restrict__ Wct, const float* __restrict__ bc,
    float* __restrict__ out, float* __restrict__ partials,
    uint* __restrict__ ctr)
{
    __shared__ ushort Asm[128 * 128];
    __shared__ ushort Bsm[128 * 128];
    __shared__ float wred[4];
    __shared__ float ssc;
    f32x4 acc[4][4] = {};
    const int tile = blockIdx.x;
    gemm_core(X, agg, Wct, 2, tile, Asm, Bsm, acc);

    const int tid = threadIdx.x, l = tid & 63, w = tid >> 6;
    const int wm = (w >> 1) * 64, wn = (w & 1) * 64;
    const size_t row0 = (size_t)tile * 128;

    float bcol[4];
#pragma unroll
    for (int n = 0; n < 4; ++n) bcol[n] = bc[wn + n * 16 + (l & 15)];
    float lsum = 0.f;
#pragma unroll
    for (int m = 0; m < 4; ++m)
#pragma unroll
        for (int n = 0; n < 4; ++n)
#pragma unroll
            for (int r = 0; r < 4; ++r) {
                float v = fmaxf(acc[m][n][r] + bcol[n], 0.f);
                acc[m][n][r] = v;                    // keep relu'd value
                lsum += v * v;
            }
#pragma unroll
    for (int off = 32; off > 0; off >>= 1) lsum += __shfl_down(lsum, off);
    if (l == 0) wred[w] = lsum;
    __syncthreads();
    if (tid == 0) {
        partials[tile] = wred[0] + wred[1] + wred[2] + wred[3];
        __threadfence();                             // release partials
        __hip_atomic_fetch_add(ctr, 1u, __ATOMIC_ACQ_REL,
                               __HIP_MEMORY_SCOPE_AGENT);
        while (__hip_atomic_load(ctr, __ATOMIC_ACQUIRE,
                                 __HIP_MEMORY_SCOPE_AGENT) < 256u)
            __builtin_amdgcn_s_sleep(8);
        float s = 0.f;
        const int bb = tile >> 4;                    // batch of this tile
#pragma unroll
        for (int i = 0; i < 16; ++i)
            s += __hip_atomic_load(&partials[bb * 16 + i], __ATOMIC_RELAXED,
                                   __HIP_MEMORY_SCOPE_AGENT);
        float norm = sqrtf(s);
        ssc = (norm > 0.f) ? (1.f / norm) : 0.f;     // div_no_nan
    }
    __syncthreads();
    const float sc = ssc;
#pragma unroll
    for (int m = 0; m < 4; ++m) {
        int rbase = wm + m * 16 + ((l >> 4) << 2);
#pragma unroll
        for (int n = 0; n < 4; ++n) {
            int col = wn + n * 16 + (l & 15);
#pragma unroll
            for (int r = 0; r < 4; ++r)
                out[(row0 + rbase + r) * 128 + col] = acc[m][n][r] * sc;
        }
    }
}

extern "C" void kernel_launch(void* const* d_in, const int* in_sizes, int n_in,
                              void* d_out, int out_size, void* d_ws, size_t ws_size,
                              hipStream_t stream) {
    const float* A  = (const float*)d_in[0];
    const float* X  = (const float*)d_in[1];
    const float* Wa = (const float*)d_in[2];
    const float* ba = (const float*)d_in[3];
    const float* Wc = (const float*)d_in[4];
    const float* bc = (const float*)d_in[5];
    const int*  nsp = (const int*)d_in[6];

    float* out = (float*)d_out;
    char* ws = (char*)d_ws;
    ushort* H        = (ushort*)ws;                              // 8 MB
    ushort* agg      = (ushort*)(ws + (8u << 20));               // 8 MB
    ushort* Wat      = (ushort*)(ws + (16u << 20));              // 32 KB
    ushort* Wct      = (ushort*)(ws + (16u << 20) + 32768);      // 64 KB
    float*  partials = (float*) (ws + (16u << 20) + 131072);     // 1 KB
    uint*   ctr      = (uint*)  (ws + (16u << 20) + 132096);     // 4 B

    // Wa -> bf16 transposed + zero barrier counter
    prep_w_k<<<64, 256, 0, stream>>>(Wa, Wat, ctr);
    // K1: H = relu(X @ Wa + ba), bf16
    gemm_k1_k<<<256, 256, 0, stream>>>(X, Wat, ba, H);
    // K2: agg = max over first-S neighbors (+ folded Wct prep blocks >= 8192)
    agg_k<<<8192 + 128, 256, 0, stream>>>(A, (const uint*)H, ba, (uint*)agg,
                                          nsp, Wc, Wct);
    // K3: GEMM + grid barrier + in-register normalize (K5 eliminated)
    gemm_k3_k<<<256, 256, 0, stream>>>(X, agg, Wct, bc, out, partials, ctr);
}